// Round 3
// baseline (982.591 us; speedup 1.0000x reference)
//
#include <hip/hip_runtime.h>
#include <math.h>

#define C 128
#define B 4096
#define NNODES 500000
#define NOUT 4
#define KTOT 384   // 2C (q_star) + C (h0)

// ---------------------------------------------------------------------------
// ws layout (fp32 elements):
//   h0 [B*C] | c0 [B*C] | q_star [B*2C] | gates [B*4C] | e_ws [NNODES]
//   seg_start [B] int32 | seg_end [B] int32
// ---------------------------------------------------------------------------

__global__ void init_state(const float* __restrict__ h, float* __restrict__ h0,
                           float* __restrict__ c0, float* __restrict__ q_star,
                           int* __restrict__ seg_start, int* __restrict__ seg_end) {
    int idx = blockIdx.x * blockDim.x + threadIdx.x;
    if (idx < B * 2 * C) q_star[idx] = 0.f;
    if (idx < B * C) { float t = h[idx]; h0[idx] = t; c0[idx] = t; }
    if (idx < B)     { seg_start[idx] = 0; seg_end[idx] = 0; }
}

__global__ void seg_bounds(const int* __restrict__ batch, int* __restrict__ seg_start,
                           int* __restrict__ seg_end) {
    int n = blockIdx.x * blockDim.x + threadIdx.x;
    if (n >= NNODES) return;
    int b = batch[n];
    if (n == 0 || batch[n - 1] != b) seg_start[b] = n;
    if (n == NNODES - 1 || batch[n + 1] != b) seg_end[b] = n + 1;
}

// ---------------------------------------------------------------------------
// lstm_gemm: unchanged from R1 (not the bottleneck this round).
// ---------------------------------------------------------------------------
#define BM 64
#define BN 64
#define BK 16
#define LDP 68

__global__ __launch_bounds__(256) void lstm_gemm(
    const float* __restrict__ q_star, const float* __restrict__ h0,
    const float* __restrict__ W_ih, const float* __restrict__ W_hh,
    const float* __restrict__ b_ih, const float* __restrict__ b_hh,
    float* __restrict__ gates) {
    __shared__ float As[BK][LDP];
    __shared__ float Bs[BK][LDP];

    const int bm0 = blockIdx.x * BM;
    const int jn0 = blockIdx.y * BN;
    const int tid = threadIdx.x;
    const int tx = tid & 15;
    const int ty = tid >> 4;

    const int st_row = tid >> 2;
    const int st_k   = (tid & 3) << 2;

    float acc[4][4] = {{0.f}};

    for (int k0 = 0; k0 < KTOT; k0 += BK) {
        float4 av, bv;
        {
            const int gb = bm0 + st_row;
            if (k0 < 256)
                av = *(const float4*)(q_star + (size_t)gb * 256 + (k0 + st_k));
            else
                av = *(const float4*)(h0 + (size_t)gb * 128 + (k0 - 256 + st_k));
            const int gj = jn0 + st_row;
            if (k0 < 256)
                bv = *(const float4*)(W_ih + (size_t)gj * 256 + (k0 + st_k));
            else
                bv = *(const float4*)(W_hh + (size_t)gj * 128 + (k0 - 256 + st_k));
        }
        __syncthreads();
        As[st_k + 0][st_row] = av.x;
        As[st_k + 1][st_row] = av.y;
        As[st_k + 2][st_row] = av.z;
        As[st_k + 3][st_row] = av.w;
        Bs[st_k + 0][st_row] = bv.x;
        Bs[st_k + 1][st_row] = bv.y;
        Bs[st_k + 2][st_row] = bv.z;
        Bs[st_k + 3][st_row] = bv.w;
        __syncthreads();

#pragma unroll
        for (int kk = 0; kk < BK; ++kk) {
            const float4 a4 = *(const float4*)&As[kk][ty << 2];
            const float4 b4 = *(const float4*)&Bs[kk][tx << 2];
            const float a[4] = {a4.x, a4.y, a4.z, a4.w};
            const float bb[4] = {b4.x, b4.y, b4.z, b4.w};
#pragma unroll
            for (int i = 0; i < 4; ++i)
#pragma unroll
                for (int j = 0; j < 4; ++j)
                    acc[i][j] = fmaf(a[i], bb[j], acc[i][j]);
        }
    }

    const int jj = jn0 + (tx << 2);
    const float4 bi = *(const float4*)(b_ih + jj);
    const float4 bh = *(const float4*)(b_hh + jj);
    const float bias[4] = {bi.x + bh.x, bi.y + bh.y, bi.z + bh.z, bi.w + bh.w};
#pragma unroll
    for (int i = 0; i < 4; ++i) {
        const int gb = bm0 + (ty << 2) + i;
        float4 o;
        o.x = acc[i][0] + bias[0];
        o.y = acc[i][1] + bias[1];
        o.z = acc[i][2] + bias[2];
        o.w = acc[i][3] + bias[3];
        *(float4*)(gates + (size_t)gb * (4 * C) + jj) = o;
    }
}

__global__ void lstm_act(const float* __restrict__ gates, float* __restrict__ c0,
                         float* __restrict__ h0, float* __restrict__ q_star) {
    int idx = blockIdx.x * blockDim.x + threadIdx.x;
    if (idx >= B * C) return;
    int b = idx / C, c = idx % C;
    const float* g = gates + (size_t)b * 4 * C;
    float ii = g[c];
    float ff = g[C + c];
    float gg = g[2 * C + c];
    float oo = g[3 * C + c];
    float si = 1.f / (1.f + __expf(-ii));
    float sf = 1.f / (1.f + __expf(-ff));
    float so = 1.f / (1.f + __expf(-oo));
    float tg = tanhf(gg);
    float cn = sf * c0[idx] + si * tg;
    float hn = so * tanhf(cn);
    c0[idx] = cn;
    h0[idx] = hn;
    q_star[(size_t)b * 2 * C + c] = hn;
}

// ---------------------------------------------------------------------------
// Attention, MLP-maximized. One block (4 waves) per segment.
// Lane mapping: slot = lane>>2 (16 node slots/wave), q4 = lane&3,
// each lane owns channels [q4*32, q4*32+32) = 8 float4.
// Per wave-iteration: 16 nodes, 8 KB of loads issued before any wait.
// Guards are clamped-address + predicated-contribution (no control flow
// around loads -> compiler batches all loads).
// ---------------------------------------------------------------------------
__global__ __launch_bounds__(256) void attention(
    const float* __restrict__ k, const float* __restrict__ v,
    const float* __restrict__ h0, const int* __restrict__ seg_start,
    const int* __restrict__ seg_end, float* __restrict__ e_ws,
    float* __restrict__ q_star, float* __restrict__ out, int t) {
    const int b = blockIdx.x;
    const int tid = threadIdx.x;
    const int w = tid >> 6;
    const int lane = tid & 63;
    const int slot = lane >> 2;
    const int q4 = lane & 3;
    const int ch = q4 << 5;     // 32 channels per lane

    __shared__ float red[4];
    __shared__ float racc[4][C];

    const int s0 = seg_start[b];
    const int s1 = seg_end[b];

    if (s1 <= s0) {   // empty segment: uniform path, safe early return
        if (tid < C) {
            out[(size_t)b * (NOUT * C) + t * C + tid] = 0.f;
            q_star[(size_t)b * 2 * C + C + tid] = 0.f;
        }
        return;
    }

    float4 q[8];
#pragma unroll
    for (int i = 0; i < 8; ++i)
        q[i] = *(const float4*)(h0 + (size_t)b * C + ch + 4 * i);

    // ---- P1: scores + running max ----
    float m = -INFINITY;
    for (int n0 = s0 + (w << 4); n0 < s1; n0 += 64) {
        int n = n0 + slot;
        const bool valid = n < s1;
        n = valid ? n : s1 - 1;
        const float* kp = k + (size_t)n * C + ch;
        float4 kv[8];
#pragma unroll
        for (int i = 0; i < 8; ++i) kv[i] = *(const float4*)(kp + 4 * i);
        float p0 = 0.f, p1 = 0.f, p2 = 0.f, p3 = 0.f;
#pragma unroll
        for (int i = 0; i < 8; ++i) {
            p0 = fmaf(kv[i].x, q[i].x, p0);
            p1 = fmaf(kv[i].y, q[i].y, p1);
            p2 = fmaf(kv[i].z, q[i].z, p2);
            p3 = fmaf(kv[i].w, q[i].w, p3);
        }
        float part = (p0 + p1) + (p2 + p3);
        part += __shfl_xor(part, 1);
        part += __shfl_xor(part, 2);
        if (valid) {
            if (q4 == 0) e_ws[n] = part;
            m = fmaxf(m, part);
        }
    }
    m = fmaxf(m, __shfl_xor(m, 4));
    m = fmaxf(m, __shfl_xor(m, 8));
    m = fmaxf(m, __shfl_xor(m, 16));
    m = fmaxf(m, __shfl_xor(m, 32));
    if (lane == 0) red[w] = m;
    __syncthreads();
    const float M = fmaxf(fmaxf(red[0], red[1]), fmaxf(red[2], red[3]));
    __syncthreads();

    // ---- sum of exp (e_ws is L2-hot) ----
    float s = 0.f;
    for (int n = s0 + tid; n < s1; n += 256) s += __expf(e_ws[n] - M);
#pragma unroll
    for (int off = 32; off >= 1; off >>= 1) s += __shfl_xor(s, off);
    if (lane == 0) red[w] = s;
    __syncthreads();
    const float S = red[0] + red[1] + red[2] + red[3];
    const float inv = 1.f / (S + 1e-16f);

    // ---- P2: weighted v accumulate (streaming, 8 KB/wave in flight) ----
    float4 A[8];
#pragma unroll
    for (int i = 0; i < 8; ++i) A[i] = make_float4(0.f, 0.f, 0.f, 0.f);
    for (int n0 = s0 + (w << 4); n0 < s1; n0 += 64) {
        int n = n0 + slot;
        const bool valid = n < s1;
        n = valid ? n : s1 - 1;
        const float e = e_ws[n];
        const float* vp = v + (size_t)n * C + ch;
        float4 vv[8];
#pragma unroll
        for (int i = 0; i < 8; ++i) vv[i] = *(const float4*)(vp + 4 * i);
        const float p = valid ? __expf(e - M) * inv : 0.f;
#pragma unroll
        for (int i = 0; i < 8; ++i) {
            A[i].x = fmaf(p, vv[i].x, A[i].x);
            A[i].y = fmaf(p, vv[i].y, A[i].y);
            A[i].z = fmaf(p, vv[i].z, A[i].z);
            A[i].w = fmaf(p, vv[i].w, A[i].w);
        }
    }
    // reduce across the 16 node slots (lanes sharing q4)
#pragma unroll
    for (int off = 4; off <= 32; off <<= 1) {
#pragma unroll
        for (int i = 0; i < 8; ++i) {
            A[i].x += __shfl_xor(A[i].x, off);
            A[i].y += __shfl_xor(A[i].y, off);
            A[i].z += __shfl_xor(A[i].z, off);
            A[i].w += __shfl_xor(A[i].w, off);
        }
    }
    if (slot == 0) {
#pragma unroll
        for (int i = 0; i < 8; ++i) *(float4*)&racc[w][ch + 4 * i] = A[i];
    }
    __syncthreads();

    if (tid < C) {
        const float r = (racc[0][tid] + racc[1][tid]) + (racc[2][tid] + racc[3][tid]);
        out[(size_t)b * (NOUT * C) + t * C + tid] = r;
        q_star[(size_t)b * 2 * C + C + tid] = r;
    }
}

// ---------------------------------------------------------------------------
extern "C" void kernel_launch(void* const* d_in, const int* in_sizes, int n_in,
                              void* d_out, int out_size, void* d_ws, size_t ws_size,
                              hipStream_t stream) {
    const float* k    = (const float*)d_in[0];
    const float* v    = (const float*)d_in[1];
    const float* h    = (const float*)d_in[2];
    const float* W_ih = (const float*)d_in[3];
    const float* W_hh = (const float*)d_in[4];
    const float* b_ih = (const float*)d_in[5];
    const float* b_hh = (const float*)d_in[6];
    const int*   batch = (const int*)d_in[7];
    float* out = (float*)d_out;

    float* ws      = (float*)d_ws;
    float* h0      = ws;
    float* c0      = h0 + (size_t)B * C;
    float* q_star  = c0 + (size_t)B * C;
    float* gates   = q_star + (size_t)B * 2 * C;
    float* e_ws    = gates + (size_t)B * 4 * C;
    int*   sstart  = (int*)(e_ws + NNODES);
    int*   send    = sstart + B;

    init_state<<<(B * 2 * C + 255) / 256, 256, 0, stream>>>(h, h0, c0, q_star, sstart, send);
    seg_bounds<<<(NNODES + 255) / 256, 256, 0, stream>>>(batch, sstart, send);

    for (int t = 0; t < NOUT; ++t) {
        lstm_gemm<<<dim3(B / BM, (4 * C) / BN), 256, 0, stream>>>(
            q_star, h0, W_ih, W_hh, b_ih, b_hh, gates);
        lstm_act<<<(B * C + 255) / 256, 256, 0, stream>>>(gates, c0, h0, q_star);
        attention<<<B, 256, 0, stream>>>(k, v, h0, sstart, send, e_ws, q_star, out, t);
    }
}